// Round 3
// baseline (244.620 us; speedup 1.0000x reference)
//
#include <hip/hip_runtime.h>
#include <hip/hip_bf16.h>

#define NS 512
#define NV 32000
#define NB 16
#define NT 128

#ifndef __has_builtin
#define __has_builtin(x) 0
#endif

typedef int v8i __attribute__((ext_vector_type(8)));
typedef float v4f __attribute__((ext_vector_type(4)));

// ---------------------------------------------------------------------------
// e4m3fn (OCP) encode, x >= 0.
// ---------------------------------------------------------------------------
__device__ inline unsigned enc_e4m3(float x) {
    x = fminf(x, 448.0f);
    unsigned u = __float_as_uint(x);
    if (x < 0.015625f) {
        return (unsigned)(int)rintf(x * 512.0f);
    }
    unsigned u2 = u + 0x7FFFFu + ((u >> 20) & 1u);
    return (((u2 >> 23) - 120u) << 3) | ((u2 >> 20) & 7u);
}

__device__ inline unsigned pack4_e4m3(float a, float b, float c, float d) {
#if __has_builtin(__builtin_amdgcn_cvt_pk_fp8_f32)
    int v = __builtin_amdgcn_cvt_pk_fp8_f32(a, b, 0, false);
    v = __builtin_amdgcn_cvt_pk_fp8_f32(c, d, v, true);
    return (unsigned)v;
#else
    return enc_e4m3(a) | (enc_e4m3(b) << 8) | (enc_e4m3(c) << 16) | (enc_e4m3(d) << 24);
#endif
}

// DPP all-lane butterfly reduce within each row of 16 lanes.
#define DPPMAX(x, ctrl) \
    x = fmaxf(x, __int_as_float(__builtin_amdgcn_mov_dpp(__float_as_int(x), ctrl, 0xF, 0xF, true)))
#define DPPADD(x, ctrl) \
    x = x + __int_as_float(__builtin_amdgcn_mov_dpp(__float_as_int(x), ctrl, 0xF, 0xF, true))

#define UMX(a, b) ((a) > (b) ? (a) : (b))

__device__ inline unsigned bytemax8(unsigned a, unsigned b) {
    unsigned m0 = UMX(a & 255u, b & 255u);
    unsigned m1 = UMX((a >> 8) & 255u, (b >> 8) & 255u);
    unsigned m2 = UMX((a >> 16) & 255u, (b >> 16) & 255u);
    unsigned m3 = UMX(a >> 24, b >> 24);
    return UMX(UMX(m0, m1), UMX(m2, m3));
}

// ---------------------------------------------------------------------------
// K1a: per-state logZ over vocab + emission gather, COALESCED store to
// em_lin_T[s][j] = exp(em[s][ids_j]) / Z_s * 2^-18.
// ---------------------------------------------------------------------------
__global__ __launch_bounds__(256) void k_emtok_T(
    const float* __restrict__ em, const int* __restrict__ ids,
    float* __restrict__ em_lin_T)
{
    const int s   = blockIdx.x;
    const int tid = threadIdx.x;
    const float* row = em + (size_t)s * NV;

    int idv[8];
#pragma unroll
    for (int k = 0; k < 8; ++k) idv[k] = ids[tid + 256 * k];
    float g[8];
#pragma unroll
    for (int k = 0; k < 8; ++k) g[k] = row[idv[k]];

    float sum = 0.f;
    const float4* row4 = (const float4*)row;
#pragma unroll 4
    for (int i = 0; i < 31; ++i) {
        float4 v = row4[tid + 256 * i];
        sum += __expf(v.x) + __expf(v.y) + __expf(v.z) + __expf(v.w);
    }
    sum += __expf(row[31744 + tid]);

#pragma unroll
    for (int off = 32; off; off >>= 1) sum += __shfl_down(sum, off);
    __shared__ float red[4];
    __shared__ float s_scale;
    if ((tid & 63) == 0) red[tid >> 6] = sum;
    __syncthreads();
    if (tid == 0) s_scale = (1.0f / ((red[0] + red[1]) + (red[2] + red[3]))) * 0x1p-18f;
    __syncthreads();
    const float scale = s_scale;

#pragma unroll
    for (int k = 0; k < 8; ++k)
        em_lin_T[(size_t)s * (NB * NT) + tid + 256 * k] = __expf(g[k]) * scale;
}

// ---------------------------------------------------------------------------
// K1b: transpose em_lin_T [512][2048] -> em_lin [2048][512], with the state
// dimension PERMUTED so k_scan can read its 4 per-thread emission values as
// one float4:  perm(s) = (s & ~63) | ((s & 15) << 2) | ((s >> 4) & 3)
// (state s = w*64 + 16*nt + lc  ->  w*64 + lc*4 + nt).
// ---------------------------------------------------------------------------
__global__ __launch_bounds__(256) void k_tr(
    const float* __restrict__ emT, float* __restrict__ em_lin)
{
    __shared__ float tile[32][33];
    const int jb = blockIdx.x * 32;
    const int sb = blockIdx.y * 32;
    const int cc = threadIdx.x & 31;
    const int rr = threadIdx.x >> 5;
#pragma unroll
    for (int i = 0; i < 4; ++i) {
        int r = rr + 8 * i;
        tile[r][cc] = emT[(size_t)(sb + r) * (NB * NT) + jb + cc];
    }
    __syncthreads();
#pragma unroll
    for (int i = 0; i < 4; ++i) {
        int r = rr + 8 * i;
        int s = sb + cc;
        int ps = (s & ~63) | ((s & 15) << 2) | ((s >> 4) & 3);
        em_lin[(size_t)(jb + r) * NS + ps] = tile[cc][r];
    }
}

// ---------------------------------------------------------------------------
// K2a: zscale[k] = 1024 / sum_d exp(tm[k][d])
// ---------------------------------------------------------------------------
__global__ __launch_bounds__(64) void k_z(
    const float* __restrict__ tm, float* __restrict__ zscale)
{
    const int k    = blockIdx.x;
    const int lane = threadIdx.x;
    const float* row = tm + (size_t)k * NS;

    float4 a = ((const float4*)row)[lane * 2];
    float4 b = ((const float4*)row)[lane * 2 + 1];
    float sum = ((__expf(a.x) + __expf(a.y)) + (__expf(a.z) + __expf(a.w)))
              + ((__expf(b.x) + __expf(b.y)) + (__expf(b.z) + __expf(b.w)));
#pragma unroll
    for (int off = 32; off; off >>= 1) sum += __shfl_down(sum, off);
    if (lane == 0) zscale[k] = 1024.0f / sum;
}

// ---------------------------------------------------------------------------
// K2b: PT[d][k] = exp(tm[k][d]) * zscale[k], e4m3 fp8, LDS-transposed tiles.
// ---------------------------------------------------------------------------
__global__ __launch_bounds__(256) void k_pt2(
    const float* __restrict__ tm, const float* __restrict__ zscale,
    unsigned char* __restrict__ PT)
{
    __shared__ float tile[64][65];
    __shared__ float zs[64];
    const int kb  = blockIdx.x * 64;
    const int db  = blockIdx.y * 64;
    const int tid = threadIdx.x;
    const int c   = tid & 63;
    const int r0  = tid >> 6;

    if (tid < 64) zs[tid] = zscale[kb + tid];
#pragma unroll
    for (int i = 0; i < 16; ++i) {
        int r = r0 + 4 * i;
        tile[r][c] = tm[(size_t)(kb + r) * NS + db + c];
    }
    __syncthreads();

    const int d  = tid >> 2;
    const int ks = (tid & 3) * 16;
    unsigned px[4];
#pragma unroll
    for (int gq = 0; gq < 4; ++gq) {
        int k0 = ks + gq * 4;
        px[gq] = pack4_e4m3(__expf(tile[k0 + 0][d]) * zs[k0 + 0],
                            __expf(tile[k0 + 1][d]) * zs[k0 + 1],
                            __expf(tile[k0 + 2][d]) * zs[k0 + 2],
                            __expf(tile[k0 + 3][d]) * zs[k0 + 3]);
    }
    uint4 o; o.x = px[0]; o.y = px[1]; o.z = px[2]; o.w = px[3];
    *(uint4*)(PT + (size_t)(db + d) * NS + kb + ks) = o;
}

// ---------------------------------------------------------------------------
// K3 v7: VALU-trimmed single-barrier step (v6 + scale-batch fix).
//   - fp8 pack uses the EXACT wave-local max E_w (no saturation risk).
//   - Cross-wave reference exponents M̂[b] are LAGGED (M(t-1), maintained by
//     4 lanes of wave 0 in a double-buffered dword mbuf; byte b = batch b).
//     Any per-batch reference is EXACT: it re-centers f32 alpha by a power
//     of 2 and gsum compensates exactly -- PROVIDED batch-b A-rows use
//     M̂[b].  v6's bug: it used M̂[lq] (thread's output batch) for the scale
//     bytes; correct is M̂[bA] (the A-ROW batch, bA = lc>>2).  gsum uses
//     M̂[lq].  Both extracted from ONE mbuf dword read.
//   - wmE2 laid out [h][batch][kt] so each consumer reads its 4 scale
//     exponents as ONE LDS dword.
//   - em_lin state-permuted (see k_tr): emission prefetch is one float4.
//   - A fragments ds_read directly into v8i halves; kt=0 MFMA uses a
//     loop-invariant zero accumulator.
// ---------------------------------------------------------------------------
__global__ __launch_bounds__(512, 2) void k_scan(
    const float* __restrict__ em_lin, const unsigned char* __restrict__ PT,
    const float* __restrict__ p, float* __restrict__ out)
{
    const int bb  = blockIdx.x;        // batch group: global batches bb*4+0..3
    const int tid = threadIdx.x;
    const int w   = tid >> 6;          // wave 0..7
    const int l   = tid & 63;          // lane
    const int lc  = l & 15;            // state-col within 16-tile
    const int lq  = l >> 4;            // local batch 0..3

    __shared__ unsigned Ew[2][16 * 128];                 // 16 KB, double-buffered
    __shared__ __align__(4) unsigned char wmE2[2][32];   // [buf][h*16 + b*4 + kt]
    __shared__ __align__(4) unsigned char mbuf[2][4];    // lagged M̂, byte b = batch b
    __shared__ float    wm2[8][4];
    __shared__ float    sbuf[4];

    // ---- load B fragments (P, once) ----
    v8i B[4][4];
#pragma unroll
    for (int nt = 0; nt < 4; ++nt) {
#pragma unroll
        for (int kt = 0; kt < 4; ++kt) {
            const uint4* src = (const uint4*)(PT + (size_t)((w * 4 + nt) * 16 + lc) * NS + kt * 128 + lq * 32);
            v8i bb8;
            *(uint4*)&bb8       = src[0];
            *((uint4*)&bb8 + 1) = src[1];
            B[nt][kt] = bb8;
        }
    }

    // ---- prior softmax denominator ----
    float zp = 0.f;
#pragma unroll
    for (int i = 0; i < 8; ++i) zp += __expf(p[l * 8 + i]);
    DPPADD(zp, 0x128); DPPADD(zp, 0x124); DPPADD(zp, 0xB1); DPPADD(zp, 0x4E);
    float Zp = __int_as_float(__builtin_amdgcn_readlane(__float_as_int(zp), 0))
             + __int_as_float(__builtin_amdgcn_readlane(__float_as_int(zp), 16))
             + __int_as_float(__builtin_amdgcn_readlane(__float_as_int(zp), 32))
             + __int_as_float(__builtin_amdgcn_readlane(__float_as_int(zp), 48));
    const float invZp = 1.0f / Zp;

    const int dbase0 = w * 64 + lc;          // state d for nt: dbase0 + 16*nt
    const int gb     = bb * 4 + lq;          // global batch of this thread

    // ---- alpha_0 (linear; 2^-18 embedded in em_lin -> shift starts at 18) ----
    // permuted em layout: thread's 4 states are contiguous at w*64 + lc*4
    const float* epb0 = em_lin + (size_t)gb * (NT * NS) + (w * 64 + lc * 4);
    v4f e0 = *(const v4f*)epb0;
    float alpha[4];
#pragma unroll
    for (int nt = 0; nt < 4; ++nt)
        alpha[nt] = __expf(p[dbase0 + 16 * nt]) * invZp * e0[nt];

    int gsum = 18;
    const unsigned sel1 = (l & 1) ? 0x07030501u : 0x02060004u;
    const unsigned sel2 = (l & 2) ? 0x07060302u : 0x01000504u;
    const int mrow = 4 * lq + (l & 3);

    // hoisted, t-invariant A-read uint4-indices and Ew write dword-indices
    int aidx[8];
#pragma unroll
    for (int kt = 0; kt < 4; ++kt) {
#pragma unroll
        for (int c = 0; c < 2; ++c)
            aidx[kt * 2 + c] = lc * 32 + (((kt * 8 + lq * 2 + c) ^ lc) & 31);
    }
    int widx[4];
#pragma unroll
    for (int nt = 0; nt < 4; ++nt)
        widx[nt] = mrow * 128 + ((((w * 4 + nt) ^ mrow) & 31) << 2) + (lc >> 2);

    // A-row held by this lane is row lc -> batch bA = lc>>2.
    const int bA = lc >> 2;
    const int h  = lq >> 1;                 // producer wave w' = 2*kt + h
    const int wexp_w = (w & 1) * 16 + lq * 4 + (w >> 1);   // my wmE2 byte slot
    const int wexp_r = h * 16 + bA * 4;                    // my scale dword slot
    const unsigned shA = (unsigned)(bA << 3);
    const unsigned shQ = (unsigned)(lq << 3);

    const float* epb = epb0 + NS;           // emission pointer, stepped by NS

    // ---- seed wmE2[1]/mbuf[1] with E(0)/M(0) ----
    {
        float mx = fmaxf(fmaxf(alpha[0], alpha[1]), fmaxf(alpha[2], alpha[3]));
        DPPMAX(mx, 0x128); DPPMAX(mx, 0x124); DPPMAX(mx, 0xB1); DPPMAX(mx, 0x4E);
        unsigned E = __float_as_uint(mx) >> 23;
        E = E > 1u ? E : 1u;
        if (lc == 0) wmE2[1][wexp_w] = (unsigned char)E;
    }
    __syncthreads();
    if (tid < 4) {
        const unsigned u0 = *(const unsigned*)&wmE2[1][tid * 4];
        const unsigned u1 = *(const unsigned*)&wmE2[1][16 + tid * 4];
        mbuf[1][tid] = (unsigned char)bytemax8(u0, u1);
    }
    // (benign race: t=1 rewrites wmE2[1] with the identical E(0) bytes)

    const v4f CZ = {0.f, 0.f, 0.f, 0.f};

    for (int t = 1; t < NT; ++t) {
        const int buf = t & 1;
        unsigned* EwB = &Ew[buf][0];

        // ---- prefetch em (consumed at end of iteration) ----
        v4f epf = *(const v4f*)epb;
        epb += NS;

        // ---- per-batch WAVE-LOCAL max (row of 16 = one batch) ----
        float mx = fmaxf(fmaxf(alpha[0], alpha[1]), fmaxf(alpha[2], alpha[3]));
        DPPMAX(mx, 0x128); DPPMAX(mx, 0x124); DPPMAX(mx, 0xB1); DPPMAX(mx, 0x4E);
        unsigned E = __float_as_uint(mx) >> 23;
        E = E > 1u ? E : 1u;
        const float sc = __uint_as_float((261u - E) << 23);   // 2^(134-E)

        // ---- e -> fp8 (LOCAL scale), DPP 4x4 byte transpose, Ew write ----
#pragma unroll
        for (int nt = 0; nt < 4; ++nt) {
            unsigned dw = pack4_e4m3(alpha[nt] * sc, 0.f, 0.f, 0.f);
            int tmp = __builtin_amdgcn_mov_dpp((int)dw, 0xB1, 0xF, 0xF, true);
            dw = __builtin_amdgcn_perm(dw, (unsigned)tmp, sel1);
            tmp = __builtin_amdgcn_mov_dpp((int)dw, 0x4E, 0xF, 0xF, true);
            dw = __builtin_amdgcn_perm(dw, (unsigned)tmp, sel2);
            EwB[widx[nt]] = dw;
        }
        if (lc == 0) wmE2[buf][wexp_w] = (unsigned char)E;
        __syncthreads();                                    // the ONLY barrier

        // ---- A fragments from LDS (hoisted swizzled indices) ----
        v8i A[4];
        const uint4* eb4 = (const uint4*)EwB;
#pragma unroll
        for (int kt = 0; kt < 4; ++kt) {
            v8i aa;
            *(uint4*)&aa       = eb4[aidx[kt * 2 + 0]];
            *((uint4*)&aa + 1) = eb4[aidx[kt * 2 + 1]];
            A[kt] = aa;
        }

        // ---- wave0 maintains the lagged reference: mbuf[buf^1] = M(t) ----
        if (tid < 4) {
            const unsigned u0 = *(const unsigned*)&wmE2[buf][tid * 4];
            const unsigned u1 = *(const unsigned*)&wmE2[buf][16 + tid * 4];
            mbuf[buf ^ 1][tid] = (unsigned char)bytemax8(u0, u1);
        }

        // ---- lagged per-batch references from ONE mbuf dword ----
        const unsigned mdw = *(const unsigned*)&mbuf[buf][0];
        const int MhA = (int)((mdw >> shA) & 255u);   // A-row batch -> scale base
        const int MhQ = (int)((mdw >> shQ) & 255u);   // thread batch -> gsum
        gsum += MhQ - 126;

        // ---- per-kt A-scale bytes from ONE wmE2 dword ----
        const unsigned dwE = *(const unsigned*)&wmE2[buf][wexp_r];
        const int base = 127 - MhA;
        int s0 = (int)(dwE & 255u) + base;         s0 = s0 < 0 ? 0 : (s0 > 254 ? 254 : s0);
        int s1 = (int)((dwE >> 8) & 255u) + base;  s1 = s1 < 0 ? 0 : (s1 > 254 ? 254 : s1);
        int s2 = (int)((dwE >> 16) & 255u) + base; s2 = s2 < 0 ? 0 : (s2 > 254 ? 254 : s2);
        int s3 = (int)(dwE >> 24) + base;          s3 = s3 < 0 ? 0 : (s3 > 254 ? 254 : s3);
        const int scA[4] = { s0 * 0x01010101, s1 * 0x01010101,
                             s2 * 0x01010101, s3 * 0x01010101 };

        // ---- MFMA: Y = E . P with per-lane e8m0 A-scales ----
        v4f C[4];
#pragma unroll
        for (int nt = 0; nt < 4; ++nt)
            C[nt] = __builtin_amdgcn_mfma_scale_f32_16x16x128_f8f6f4(
                        A[0], B[nt][0], CZ, 0, 0, 0, scA[0], 0, 0x7F7F7F7F);
#pragma unroll
        for (int kt = 1; kt < 4; ++kt)
#pragma unroll
            for (int nt = 0; nt < 4; ++nt)
                C[nt] = __builtin_amdgcn_mfma_scale_f32_16x16x128_f8f6f4(
                            A[kt], B[nt][kt], C[nt], 0, 0, 0, scA[kt], 0, 0x7F7F7F7F);

        // ---- alpha update (linear); batch lq = C-row 4*lq = reg 0 ----
#pragma unroll
        for (int nt = 0; nt < 4; ++nt)
            alpha[nt] = C[nt][0] * epf[nt];
    }

    // ---- final: per-batch logsumexp over states ----
    {
        float sm = (alpha[0] + alpha[1]) + (alpha[2] + alpha[3]);
        DPPADD(sm, 0x128); DPPADD(sm, 0x124); DPPADD(sm, 0xB1); DPPADD(sm, 0x4E);
        if (lc == 0) wm2[w][lq] = sm;
        if (w == 0 && lc == 0) sbuf[lq] = (float)gsum;
    }
    __syncthreads();
    if (tid < 4) {
        float s8 = ((wm2[0][tid] + wm2[1][tid]) + (wm2[2][tid] + wm2[3][tid]))
                 + ((wm2[4][tid] + wm2[5][tid]) + (wm2[6][tid] + wm2[7][tid]));
        float L2 = __log2f(s8) + sbuf[tid];
        atomicAdd(out, -(0.693147180559945f / 16.0f) * L2);
    }
}

// ---------------------------------------------------------------------------
extern "C" void kernel_launch(void* const* d_in, const int* in_sizes, int n_in,
                              void* d_out, int out_size, void* d_ws, size_t ws_size,
                              hipStream_t stream)
{
    const int*   ids = (const int*)d_in[0];   // [16][128]
    const float* em  = (const float*)d_in[1]; // [512][32000]
    const float* tm  = (const float*)d_in[2]; // [512][512]
    const float* p   = (const float*)d_in[3]; // [512]
    float* out = (float*)d_out;

    float*          em_lin = (float*)d_ws;
    unsigned char*  PT     = (unsigned char*)d_ws + ((size_t)4 << 20);
    float*          zscale = (float*)((unsigned char*)d_ws + ((size_t)4 << 20) + ((size_t)256 << 10));
    float*          emT    = (float*)((unsigned char*)d_ws + ((size_t)4 << 20) + ((size_t)512 << 10));

    hipMemsetAsync(d_out, 0, sizeof(float), stream);

    k_emtok_T<<<NS, 256, 0, stream>>>(em, ids, emT);
    k_tr<<<dim3(64, 16), 256, 0, stream>>>(emT, em_lin);
    k_z<<<NS, 64, 0, stream>>>(tm, zscale);
    k_pt2<<<dim3(8, 8), 256, 0, stream>>>(tm, zscale, PT);
    k_scan<<<4, 512, 0, stream>>>(em_lin, PT, p, out);
}